// Round 21
// baseline (123.692 us; speedup 1.0000x reference)
//
#include <hip/hip_runtime.h>
#include <cstdint>
#include <cstddef>

#define HFEAT 128
#define FFEAT 256
#define EPB 2048  // edges per block for hist/scatter passes
#define PACK_TOTAL (FFEAT * HFEAT + HFEAT * HFEAT + HFEAT * FFEAT)  // 81920

typedef short bf16x8 __attribute__((ext_vector_type(8)));
typedef float f32x4 __attribute__((ext_vector_type(4)));
typedef unsigned short ushort8v __attribute__((ext_vector_type(8)));

static __device__ __forceinline__ unsigned short f2bf(float f) {
    unsigned u = __float_as_uint(f);
    unsigned r = (u + 0x7fff + ((u >> 16) & 1)) >> 16;  // RNE
    return (unsigned short)r;
}
static __device__ __forceinline__ float bf2f(unsigned short u) {
    return __uint_as_float((unsigned)u << 16);
}

// ---------------- weight pack helper ----------------
static __device__ __forceinline__ void pack_one(const float* __restrict__ W,
                                                ushort* __restrict__ Bp,
                                                int tid, int N) {
    int j = tid & 7;
    int lane = (tid >> 3) & 63;
    int rest = tid >> 9;
    int nct = N >> 4;
    int ct = rest % nct, kt = rest / nct;
    int k = kt * 32 + (lane >> 4) * 8 + j;
    int col = ct * 16 + (lane & 15);
    Bp[tid] = f2bf(W[(size_t)k * N + col]);
}

// ---------------- CSR build: two-level counting sort (r17 structure) ----------------
// histA also carries the weight pack (independent work, saves one launch).
__global__ __launch_bounds__(256) void histA_kernel(
    const int* __restrict__ dst, int* __restrict__ histT,
    const float* __restrict__ Wg, const float* __restrict__ W1, const float* __restrict__ W2,
    ushort* __restrict__ WgP, ushort* __restrict__ W1P, ushort* __restrict__ W2P,
    int E, int NB_C) {
    __shared__ int hist[256];
    int t = threadIdx.x, b = blockIdx.x;
    hist[t] = 0;
    __syncthreads();

    // fused weight pack (grid-stride)
    for (int idx = b * 256 + t; idx < PACK_TOTAL; idx += NB_C * 256) {
        if (idx < FFEAT * HFEAT) pack_one(Wg, WgP, idx, HFEAT);
        else if (idx < FFEAT * HFEAT + HFEAT * HFEAT) pack_one(W1, W1P, idx - FFEAT * HFEAT, HFEAT);
        else pack_one(W2, W2P, idx - FFEAT * HFEAT - HFEAT * HFEAT, FFEAT);
    }

    int lo = b * EPB, hi = min(E, lo + EPB);
    for (int i = lo + t; i < hi; i += 256)
        atomicAdd(&hist[dst[i] >> 8], 1);
    __syncthreads();
    histT[t * NB_C + b] = hist[t];
}

__global__ __launch_bounds__(256) void bsum_kernel(const int* __restrict__ in,
                                                   int* __restrict__ bsum, int n) {
    int i = blockIdx.x * 256 + threadIdx.x;
    int v = (i < n) ? in[i] : 0;
    for (int off = 32; off; off >>= 1) v += __shfl_down(v, off, 64);
    __shared__ int sh[4];
    if ((threadIdx.x & 63) == 0) sh[threadIdx.x >> 6] = v;
    __syncthreads();
    if (threadIdx.x == 0) bsum[blockIdx.x] = sh[0] + sh[1] + sh[2] + sh[3];
}

__global__ __launch_bounds__(1024) void bscan_kernel(int* __restrict__ bsum, int nb) {
    __shared__ int sh[1024];
    int t = threadIdx.x;
    int v = (t < nb) ? bsum[t] : 0;
    sh[t] = v;
    __syncthreads();
    for (int off = 1; off < 1024; off <<= 1) {
        int u = (t >= off) ? sh[t - off] : 0;
        __syncthreads();
        sh[t] += u;
        __syncthreads();
    }
    if (t < nb) bsum[t] = sh[t] - v;  // exclusive
}

__global__ __launch_bounds__(256) void escan_kernel(const int* __restrict__ in,
                                                    const int* __restrict__ boff,
                                                    int* __restrict__ out, int n) {
    __shared__ int sh[256];
    int t = threadIdx.x, i = blockIdx.x * 256 + t;
    int v = (i < n) ? in[i] : 0;
    sh[t] = v;
    __syncthreads();
    for (int off = 1; off < 256; off <<= 1) {
        int u = (t >= off) ? sh[t - off] : 0;
        __syncthreads();
        sh[t] += u;
        __syncthreads();
    }
    if (i < n) out[i] = boff[blockIdx.x] + sh[t] - v;
}

__global__ __launch_bounds__(256) void scatterC_kernel(const int* __restrict__ src,
                                                       const int* __restrict__ dst,
                                                       const int* __restrict__ scanT,
                                                       unsigned* __restrict__ packed,
                                                       int E, int NB_C) {
    __shared__ int base[256];
    __shared__ int fill[256];
    int t = threadIdx.x, b = blockIdx.x;
    base[t] = scanT[t * NB_C + b];
    fill[t] = 0;
    __syncthreads();
    int lo = b * EPB, hi = min(E, lo + EPB);
    for (int i = lo + t; i < hi; i += 256) {
        int d = dst[i], s = src[i];
        int c = d >> 8;
        int pos = base[c] + atomicAdd(&fill[c], 1);
        packed[pos] = ((unsigned)d << 16) | (unsigned)s;
    }
}

__global__ __launch_bounds__(256) void fineD_kernel(const unsigned* __restrict__ packed,
                                                    const int* __restrict__ scanT,
                                                    ushort* __restrict__ esrc,
                                                    int* __restrict__ row_ptr,
                                                    float* __restrict__ dinv,
                                                    int E, int NB_C, int n) {
    __shared__ int cnt[256];
    __shared__ int excl[256];
    int t = threadIdx.x, blk = blockIdx.x;
    int seg0 = scanT[blk * NB_C];
    int seg1 = (blk == 255) ? E : scanT[(blk + 1) * NB_C];
    cnt[t] = 0;
    __syncthreads();
    for (int i = seg0 + t; i < seg1; i += 256)
        atomicAdd(&cnt[(packed[i] >> 16) & 255], 1);
    __syncthreads();
    excl[t] = cnt[t];
    __syncthreads();
    for (int off = 1; off < 256; off <<= 1) {
        int u = (t >= off) ? excl[t - off] : 0;
        __syncthreads();
        excl[t] += u;
        __syncthreads();
    }
    int ex = excl[t] - cnt[t];  // exclusive within bucket
    int node = blk * 256 + t;
    if (node < n) {
        row_ptr[node] = seg0 + ex;
        dinv[node] = rsqrtf((float)cnt[t] + 1.0f);
        if (node == n - 1) row_ptr[n] = seg0 + ex + cnt[t];
    }
    excl[t] = ex;  // becomes fill counter
    __syncthreads();
    for (int i = seg0 + t; i < seg1; i += 256) {
        unsigned pk = packed[i];
        int dl = (pk >> 16) & 255;
        int pos = seg0 + atomicAdd(&excl[dl], 1);
        esrc[pos] = (ushort)(pk & 0xFFFF);
    }
}

// ---------------- MFMA GEMM (G1 only) with LDS-staged epilogue ----------------
template<int K, int NCT, int ACT, int AF32>
__global__ __launch_bounds__(256) void mfma_gemm(
    const void* __restrict__ A, const ushort* __restrict__ Bp,
    const float* __restrict__ bias, void* __restrict__ Cout,
    int M, int ldc, int totct) {
    constexpr int CH = NCT * 16;
    constexpr int CSTR = CH + 4;
    __shared__ float cs[128 * CSTR];

    const int tid = threadIdx.x;
    const int wid = tid >> 6, lane = tid & 63;
    const int ct0 = blockIdx.y * NCT;
    const int rowbase = blockIdx.x * 128 + wid * 32;
    const int ak = (lane >> 4) * 8;

    f32x4 acc[2][NCT];
#pragma unroll
    for (int s = 0; s < 2; s++)
#pragma unroll
        for (int c = 0; c < NCT; c++) acc[s][c] = (f32x4){0.f, 0.f, 0.f, 0.f};

    int r0 = rowbase + (lane & 15); if (r0 >= M) r0 = M - 1;
    int r1 = rowbase + 16 + (lane & 15); if (r1 >= M) r1 = M - 1;
    const float*  a0f = (const float*)A + (size_t)r0 * K + ak;
    const float*  a1f = (const float*)A + (size_t)r1 * K + ak;
    const ushort* a0b = (const ushort*)A + (size_t)r0 * K + ak;
    const ushort* a1b = (const ushort*)A + (size_t)r1 * K + ak;

#pragma unroll
    for (int kt = 0; kt < K / 32; kt++) {
        bf16x8 a0, a1;
        if (AF32) {
            float u[8], v[8];
            *(float4*)u = *(const float4*)(a0f + kt * 32);
            *(float4*)(u + 4) = *(const float4*)(a0f + kt * 32 + 4);
            *(float4*)v = *(const float4*)(a1f + kt * 32);
            *(float4*)(v + 4) = *(const float4*)(a1f + kt * 32 + 4);
#pragma unroll
            for (int j = 0; j < 8; j++) { a0[j] = (short)f2bf(u[j]); a1[j] = (short)f2bf(v[j]); }
        } else {
            a0 = *reinterpret_cast<const bf16x8*>(a0b + kt * 32);
            a1 = *reinterpret_cast<const bf16x8*>(a1b + kt * 32);
        }
        const ushort* bp = Bp + ((size_t)(kt * totct + ct0) * 64 + lane) * 8;
#pragma unroll
        for (int c = 0; c < NCT; c++) {
            bf16x8 b = *reinterpret_cast<const bf16x8*>(bp + (size_t)c * 64 * 8);
            acc[0][c] = __builtin_amdgcn_mfma_f32_16x16x32_bf16(a0, b, acc[0][c], 0, 0, 0);
            acc[1][c] = __builtin_amdgcn_mfma_f32_16x16x32_bf16(a1, b, acc[1][c], 0, 0, 0);
        }
    }

    const int ccol = lane & 15;
    const int crow = (lane >> 4) * 4;
#pragma unroll
    for (int s = 0; s < 2; s++) {
#pragma unroll
        for (int c = 0; c < NCT; c++) {
            float* dstp = cs + (size_t)(wid * 32 + s * 16 + crow) * CSTR + c * 16 + ccol;
#pragma unroll
            for (int r = 0; r < 4; r++)
                dstp[(size_t)r * CSTR] = acc[s][c][r];
        }
    }
    __syncthreads();

    const int rowblk = blockIdx.x * 128;
    const int colbase = ct0 * 16;
    if (ACT == 0 || ACT == 2) {
        constexpr int CPR = CH / 4;
        for (int i = tid; i < 128 * CPR; i += 256) {
            int row = i / CPR, c4 = (i - row * CPR) * 4;
            int grow = rowblk + row;
            if (grow >= M) continue;
            float4 v = *(const float4*)(cs + (size_t)row * CSTR + c4);
            int col = colbase + c4;
            if (bias) {
                float4 bb = *(const float4*)(bias + col);
                v.x += bb.x; v.y += bb.y; v.z += bb.z; v.w += bb.w;
            }
            if (ACT == 2) {
                v.x = 1.f / (1.f + __expf(-v.x));
                v.y = 1.f / (1.f + __expf(-v.y));
                v.z = 1.f / (1.f + __expf(-v.z));
                v.w = 1.f / (1.f + __expf(-v.w));
            }
            *(float4*)((float*)Cout + (size_t)grow * ldc + col) = v;
        }
    } else {
        constexpr int CPR = CH / 8;
        for (int i = tid; i < 128 * CPR; i += 256) {
            int row = i / CPR, c8 = (i - row * CPR) * 8;
            int grow = rowblk + row;
            if (grow >= M) continue;
            int col = colbase + c8;
            float v[8];
            *(float4*)v = *(const float4*)(cs + (size_t)row * CSTR + c8);
            *(float4*)(v + 4) = *(const float4*)(cs + (size_t)row * CSTR + c8 + 4);
            ushort8v o;
#pragma unroll
            for (int j = 0; j < 8; j++) {
                float t = v[j] + (bias ? bias[col + j] : 0.f);
                if (ACT == 1) t = t > 0.f ? t : 0.f;
                o[j] = f2bf(t);
            }
            *(ushort8v*)((ushort*)Cout + (size_t)grow * ldc + col) = o;
        }
    }
}

// ---------------- fused G2+G3, column-split: blockIdx.y = which 128-col half of fo ----------------
// Each block recomputes the cheap z phase (G2, +1.6 GF total — compute is free here)
// and does ONE G3 column pass: per-block serial chain drops from {z + 2 passes, 5
// barriers} to {z + 1 pass, 2 barriers}; grid doubles to 2*GB for latency overlap.
__global__ __launch_bounds__(256) void g2g3_kernel(
    const ushort* __restrict__ outb, const ushort* __restrict__ W1P,
    const float* __restrict__ b1, const ushort* __restrict__ W2P,
    const float* __restrict__ b2, float* __restrict__ fo, int M) {
    constexpr int ZSTR = 136;    // bf16 elems; 272 B row stride
    constexpr int CSTR = 132;    // f32 elems
    __shared__ ushort zlds[64 * ZSTR];  // 17,408 B
    __shared__ float  cs[64 * CSTR];    // 33,792 B

    const int tid = threadIdx.x;
    const int wid = tid >> 6, lane = tid & 63;
    const int rowbase = blockIdx.x * 64 + wid * 16;
    const int pass = blockIdx.y;         // which 128-col half of fo
    const int ak = (lane >> 4) * 8;
    const int ccol = lane & 15;
    const int crow4 = (lane >> 4) * 4;

    // ---- phase 1: z = relu(outb @ W1 + b1), 16 rows/wave, K=128, 128 cols
    f32x4 acc[8];
#pragma unroll
    for (int c = 0; c < 8; c++) acc[c] = (f32x4){0.f, 0.f, 0.f, 0.f};

    int r0 = rowbase + (lane & 15); if (r0 >= M) r0 = M - 1;
    const ushort* a0b = outb + (size_t)r0 * HFEAT + ak;
#pragma unroll
    for (int kt = 0; kt < 4; kt++) {
        bf16x8 a0 = *reinterpret_cast<const bf16x8*>(a0b + kt * 32);
        const ushort* bp = W1P + ((size_t)(kt * 8) * 64 + lane) * 8;
#pragma unroll
        for (int c = 0; c < 8; c++) {
            bf16x8 b = *reinterpret_cast<const bf16x8*>(bp + (size_t)c * 512);
            acc[c] = __builtin_amdgcn_mfma_f32_16x16x32_bf16(a0, b, acc[c], 0, 0, 0);
        }
    }
#pragma unroll
    for (int c = 0; c < 8; c++) {
        float bb = b1[c * 16 + ccol];
        ushort* zp = zlds + (size_t)(wid * 16 + crow4) * ZSTR + c * 16 + ccol;
#pragma unroll
        for (int r = 0; r < 4; r++) {
            float v = acc[c][r] + bb;
            v = v > 0.f ? v : 0.f;
            zp[(size_t)r * ZSTR] = f2bf(v);
        }
    }
    __syncthreads();  // z-writes before z-reads (cross-lane RAW, rule #18)

    // ---- phase 2: ONE 128-col pass (this block's half)
    const int rowblk = blockIdx.x * 64;
    const ushort* z0 = zlds + (size_t)(wid * 16 + (lane & 15)) * ZSTR + ak;
    f32x4 acc2[8];
#pragma unroll
    for (int c = 0; c < 8; c++) acc2[c] = (f32x4){0.f, 0.f, 0.f, 0.f};
#pragma unroll
    for (int kt = 0; kt < 4; kt++) {
        bf16x8 a0 = *reinterpret_cast<const bf16x8*>(z0 + kt * 32);
        const ushort* bp = W2P + ((size_t)(kt * 16 + pass * 8) * 64 + lane) * 8;
#pragma unroll
        for (int c = 0; c < 8; c++) {
            bf16x8 b = *reinterpret_cast<const bf16x8*>(bp + (size_t)c * 512);
            acc2[c] = __builtin_amdgcn_mfma_f32_16x16x32_bf16(a0, b, acc2[c], 0, 0, 0);
        }
    }
    // stage to cs (fresh buffer — only the z-read/cs-write overlap needs care: cs and
    // zlds are SEPARATE LDS regions, so no union hazard; one barrier orders stage->read)
#pragma unroll
    for (int c = 0; c < 8; c++) {
        float* dstp = cs + (size_t)(wid * 16 + crow4) * CSTR + c * 16 + ccol;
#pragma unroll
        for (int r = 0; r < 4; r++)
            dstp[(size_t)r * CSTR] = acc2[c][r];
    }
    __syncthreads();
    for (int i = tid; i < 64 * 32; i += 256) {
        int row = i >> 5, c4 = (i & 31) * 4;
        int grow = rowblk + row;
        if (grow >= M) continue;
        float4 v = *(const float4*)(cs + (size_t)row * CSTR + c4);
        int col = pass * 128 + c4;
        float4 bb = *(const float4*)(b2 + col);
        v.x = 1.f / (1.f + __expf(-(v.x + bb.x)));
        v.y = 1.f / (1.f + __expf(-(v.y + bb.y)));
        v.z = 1.f / (1.f + __expf(-(v.z + bb.z)));
        v.w = 1.f / (1.f + __expf(-(v.w + bb.w)));
        *(float4*)(fo + (size_t)grow * FFEAT + col) = v;
    }
}

// ---------------- CSR gather + fused p/q (edge-split halves) ----------------
__global__ __launch_bounds__(256) void gather_pq_kernel(
    const ushort* __restrict__ h, const int* __restrict__ row_ptr,
    const ushort* __restrict__ esrc, const float* __restrict__ dinv,
    const float* __restrict__ bg, const float* __restrict__ Wa,
    ushort* __restrict__ outb, float* __restrict__ p, float* __restrict__ q, int n) {
    int tid = threadIdx.x;
    int node = blockIdx.x * 8 + (tid >> 5);
    int half = (tid >> 4) & 1;
    int c8 = (tid & 15) * 8;
    if (node >= n) return;
    float di = dinv[node];
    int r0 = row_ptr[node], r1 = row_ptr[node + 1];
    float acc[8];
    if (half == 0) {
        ushort8v hv = *(const ushort8v*)(h + (size_t)node * HFEAT + c8);
#pragma unroll
        for (int j = 0; j < 8; j++) acc[j] = bf2f(hv[j]) * di;
    } else {
#pragma unroll
        for (int j = 0; j < 8; j++) acc[j] = 0.f;
    }
    int e = r0 + half;
    for (; e + 2 < r1; e += 4) {
        int s0 = esrc[e], s1 = esrc[e + 2];
        float d0 = dinv[s0], d1 = dinv[s1];
        ushort8v v0 = *(const ushort8v*)(h + (size_t)s0 * HFEAT + c8);
        ushort8v v1 = *(const ushort8v*)(h + (size_t)s1 * HFEAT + c8);
#pragma unroll
        for (int j = 0; j < 8; j++) acc[j] = fmaf(bf2f(v0[j]), d0, acc[j]);
#pragma unroll
        for (int j = 0; j < 8; j++) acc[j] = fmaf(bf2f(v1[j]), d1, acc[j]);
    }
    if (e < r1) {
        int s0 = esrc[e];
        float d0 = dinv[s0];
        ushort8v v0 = *(const ushort8v*)(h + (size_t)s0 * HFEAT + c8);
#pragma unroll
        for (int j = 0; j < 8; j++) acc[j] = fmaf(bf2f(v0[j]), d0, acc[j]);
    }
#pragma unroll
    for (int j = 0; j < 8; j++) acc[j] += __shfl_down(acc[j], 16, 32);
    if (half == 0) {
        float o[8];
        ushort8v ov;
#pragma unroll
        for (int j = 0; j < 8; j++) {
            o[j] = fmaf(acc[j], di, bg[c8 + j]);
            ov[j] = f2bf(o[j]);
        }
        *(ushort8v*)(outb + (size_t)node * HFEAT + c8) = ov;

        float pp = 0.f, qq = 0.f;
#pragma unroll
        for (int j = 0; j < 8; j++) {
            pp = fmaf(o[j], Wa[c8 + j], pp);
            qq = fmaf(o[j], Wa[HFEAT + c8 + j], qq);
        }
        for (int off = 8; off; off >>= 1) {
            pp += __shfl_down(pp, off, 16);
            qq += __shfl_down(qq, off, 16);
        }
        if ((tid & 31) == 0) { p[node] = pp; q[node] = qq; }
    }
}

// ---------------- adjacency scores ----------------
__global__ void adj_kernel(const int* __restrict__ k0, const int* __restrict__ k1,
                           const int2* __restrict__ na, const float* __restrict__ p,
                           const float* __restrict__ q, const float* __restrict__ ba,
                           float* __restrict__ outp, int ek, int en) {
    int e = blockIdx.x * blockDim.x + threadIdx.x;
    int tot = ek + en;
    if (e >= tot) return;
    int a, b;
    if (e < ek) { a = k0[e]; b = k1[e]; }
    else { int2 ab = na[e - ek]; a = ab.x; b = ab.y; }
    float v = p[a] + q[b] + ba[0];
    outp[e] = 1.f / (1.f + __expf(-v));
}

extern "C" void kernel_launch(void* const* d_in, const int* in_sizes, int n_in,
                              void* d_out, int out_size, void* d_ws, size_t ws_size,
                              hipStream_t stream) {
    const float* x  = (const float*)d_in[0];
    const int*   ei = (const int*)d_in[1];
    const int*   kh = (const int*)d_in[2];
    const int*   na = (const int*)d_in[3];
    const float* Wg = (const float*)d_in[4];
    const float* bg = (const float*)d_in[5];
    const float* W1 = (const float*)d_in[6];
    const float* b1 = (const float*)d_in[7];
    const float* W2 = (const float*)d_in[8];
    const float* b2 = (const float*)d_in[9];
    const float* Wa = (const float*)d_in[10];
    const float* ba = (const float*)d_in[11];

    const int N  = in_sizes[0] / FFEAT;
    const int E  = in_sizes[1] / 2;
    const int EK = in_sizes[2] / 2;
    const int EN = in_sizes[3] / 2;

    float* fo = (float*)d_out;             // feature_out [N, 256] f32
    float* ao = fo + (size_t)N * FFEAT;    // adj_out [EK+EN]

    const int NB_C = (E + EPB - 1) / EPB;  // coarse blocks (391)
    const int n2 = 256 * NB_C;             // histT elements

    char* ws = (char*)d_ws;
    ushort* h    = (ushort*)ws;  ws += (size_t)N * HFEAT * 2;   // bf16
    ushort* outb = (ushort*)ws;  ws += (size_t)N * HFEAT * 2;
    ushort* WgP  = (ushort*)ws;  ws += (size_t)FFEAT * HFEAT * 2;
    ushort* W1P  = (ushort*)ws;  ws += (size_t)HFEAT * HFEAT * 2;
    ushort* W2P  = (ushort*)ws;  ws += (size_t)HFEAT * FFEAT * 2;
    float*  dinv = (float*)ws;   ws += (size_t)N * 4;
    float*  p    = (float*)ws;   ws += (size_t)N * 4;
    float*  q    = (float*)ws;   ws += (size_t)N * 4;
    int*    row_ptr = (int*)ws;  ws += (size_t)(N + 1) * 4;
    int*    histT = (int*)ws;    ws += (size_t)n2 * 4;
    int*    scanT = (int*)ws;    ws += (size_t)n2 * 4;
    int*    bsum  = (int*)ws;    ws += (size_t)1024 * 4;
    unsigned* packed = (unsigned*)ws; ws += (size_t)E * 4;
    ushort* esrc = (ushort*)ws;  ws += (size_t)E * 2;

    const int B = 256;
    const int GX = (N + 127) / 128;
    const int GB = (N + 63) / 64;

    // CSR build via two-level counting sort (weight pack fused in histA)
    histA_kernel<<<NB_C, B, 0, stream>>>(ei + E, histT, Wg, W1, W2, WgP, W1P, W2P, E, NB_C);
    bsum_kernel<<<NB_C, B, 0, stream>>>(histT, bsum, n2);
    bscan_kernel<<<1, 1024, 0, stream>>>(bsum, NB_C);
    escan_kernel<<<NB_C, B, 0, stream>>>(histT, bsum, scanT, n2);
    scatterC_kernel<<<NB_C, B, 0, stream>>>(ei, ei + E, scanT, packed, E, NB_C);
    fineD_kernel<<<256, B, 0, stream>>>(packed, scanT, esrc, row_ptr, dinv, E, NB_C, N);

    // G1: h = bf16( x(f32) @ Wg ), in-kernel RNE convert, single pass
    mfma_gemm<FFEAT, 8, 3, 1><<<dim3(GX, 1), B, 0, stream>>>(x, WgP, nullptr, h, N, HFEAT, HFEAT / 16);

    // GCN aggregate -> outb (bf16), bias fused, p/q fused
    gather_pq_kernel<<<(N + 7) / 8, B, 0, stream>>>(h, row_ptr, esrc, dinv, bg, Wa, outb, p, q, N);

    // fused G2+G3, column-split (blockIdx.y = fo column half)
    g2g3_kernel<<<dim3(GB, 2), B, 0, stream>>>(outb, W1P, b1, W2P, b2, fo, N);

    // adjacency scores
    adj_kernel<<<(EK + EN + B - 1) / B, B, 0, stream>>>(kh, kh + EK, (const int2*)na, p, q, ba, ao, EK, EN);
}

// Round 22
// 122.651 us; speedup vs baseline: 1.0085x; 1.0085x over previous
//
#include <hip/hip_runtime.h>
#include <cstdint>
#include <cstddef>

#define HFEAT 128
#define FFEAT 256
#define EPB 4096  // edges per block for hist/scatter passes (NB_C = 196 <= 256)
#define PACK_TOTAL (FFEAT * HFEAT + HFEAT * HFEAT + HFEAT * FFEAT)  // 81920

typedef short bf16x8 __attribute__((ext_vector_type(8)));
typedef float f32x4 __attribute__((ext_vector_type(4)));
typedef unsigned short ushort8v __attribute__((ext_vector_type(8)));

static __device__ __forceinline__ unsigned short f2bf(float f) {
    unsigned u = __float_as_uint(f);
    unsigned r = (u + 0x7fff + ((u >> 16) & 1)) >> 16;  // RNE
    return (unsigned short)r;
}
static __device__ __forceinline__ float bf2f(unsigned short u) {
    return __uint_as_float((unsigned)u << 16);
}

// ---------------- weight pack helper ----------------
static __device__ __forceinline__ void pack_one(const float* __restrict__ W,
                                                ushort* __restrict__ Bp,
                                                int tid, int N) {
    int j = tid & 7;
    int lane = (tid >> 3) & 63;
    int rest = tid >> 9;
    int nct = N >> 4;
    int ct = rest % nct, kt = rest / nct;
    int k = kt * 32 + (lane >> 4) * 8 + j;
    int col = ct * 16 + (lane & 15);
    Bp[tid] = f2bf(W[(size_t)k * N + col]);
}

// ---------------- CSR build: two-level counting sort (r17 structure, EPB=4096) ----------------
__global__ __launch_bounds__(256) void histA_kernel(
    const int* __restrict__ dst, int* __restrict__ histT,
    const float* __restrict__ Wg, const float* __restrict__ W1, const float* __restrict__ W2,
    ushort* __restrict__ WgP, ushort* __restrict__ W1P, ushort* __restrict__ W2P,
    int E, int NB_C) {
    __shared__ int hist[256];
    int t = threadIdx.x, b = blockIdx.x;
    hist[t] = 0;
    __syncthreads();

    // fused weight pack (grid-stride)
    for (int idx = b * 256 + t; idx < PACK_TOTAL; idx += NB_C * 256) {
        if (idx < FFEAT * HFEAT) pack_one(Wg, WgP, idx, HFEAT);
        else if (idx < FFEAT * HFEAT + HFEAT * HFEAT) pack_one(W1, W1P, idx - FFEAT * HFEAT, HFEAT);
        else pack_one(W2, W2P, idx - FFEAT * HFEAT - HFEAT * HFEAT, FFEAT);
    }

    int lo = b * EPB, hi = min(E, lo + EPB);
    for (int i = lo + t; i < hi; i += 256)
        atomicAdd(&hist[dst[i] >> 8], 1);
    __syncthreads();
    histT[t * NB_C + b] = hist[t];
}

__global__ __launch_bounds__(256) void bsum_kernel(const int* __restrict__ in,
                                                   int* __restrict__ bsum, int n) {
    int i = blockIdx.x * 256 + threadIdx.x;
    int v = (i < n) ? in[i] : 0;
    for (int off = 32; off; off >>= 1) v += __shfl_down(v, off, 64);
    __shared__ int sh[4];
    if ((threadIdx.x & 63) == 0) sh[threadIdx.x >> 6] = v;
    __syncthreads();
    if (threadIdx.x == 0) bsum[blockIdx.x] = sh[0] + sh[1] + sh[2] + sh[3];
}

// escan with self-computed block offset (bscan kernel eliminated; NB_C <= 256 so each
// block reduces bsum[0..bx) in LDS — one load/thread)
__global__ __launch_bounds__(256) void escan_kernel(const int* __restrict__ in,
                                                    const int* __restrict__ bsum,
                                                    int* __restrict__ out, int n) {
    __shared__ int sh[256];
    int t = threadIdx.x, bx = blockIdx.x;
    // block offset = sum of bsum[0..bx)
    int v = (t < bx) ? bsum[t] : 0;
    sh[t] = v;
    __syncthreads();
    for (int off = 128; off; off >>= 1) {
        if (t < off) sh[t] += sh[t + off];
        __syncthreads();
    }
    int boff = sh[0];
    __syncthreads();
    // local chunk scan
    int i = bx * 256 + t;
    int u = (i < n) ? in[i] : 0;
    sh[t] = u;
    __syncthreads();
    for (int off = 1; off < 256; off <<= 1) {
        int w = (t >= off) ? sh[t - off] : 0;
        __syncthreads();
        sh[t] += w;
        __syncthreads();
    }
    if (i < n) out[i] = boff + sh[t] - u;
}

__global__ __launch_bounds__(256) void scatterC_kernel(const int* __restrict__ src,
                                                       const int* __restrict__ dst,
                                                       const int* __restrict__ scanT,
                                                       unsigned* __restrict__ packed,
                                                       int E, int NB_C) {
    __shared__ int base[256];
    __shared__ int fill[256];
    int t = threadIdx.x, b = blockIdx.x;
    base[t] = scanT[t * NB_C + b];
    fill[t] = 0;
    __syncthreads();
    int lo = b * EPB, hi = min(E, lo + EPB);
    for (int i = lo + t; i < hi; i += 256) {
        int d = dst[i], s = src[i];
        int c = d >> 8;
        int pos = base[c] + atomicAdd(&fill[c], 1);
        packed[pos] = ((unsigned)d << 16) | (unsigned)s;
    }
}

__global__ __launch_bounds__(256) void fineD_kernel(const unsigned* __restrict__ packed,
                                                    const int* __restrict__ scanT,
                                                    ushort* __restrict__ esrc,
                                                    int* __restrict__ row_ptr,
                                                    float* __restrict__ dinv,
                                                    int E, int NB_C, int n) {
    __shared__ int cnt[256];
    __shared__ int excl[256];
    int t = threadIdx.x, blk = blockIdx.x;
    int seg0 = scanT[blk * NB_C];
    int seg1 = (blk == 255) ? E : scanT[(blk + 1) * NB_C];
    cnt[t] = 0;
    __syncthreads();
    for (int i = seg0 + t; i < seg1; i += 256)
        atomicAdd(&cnt[(packed[i] >> 16) & 255], 1);
    __syncthreads();
    excl[t] = cnt[t];
    __syncthreads();
    for (int off = 1; off < 256; off <<= 1) {
        int u = (t >= off) ? excl[t - off] : 0;
        __syncthreads();
        excl[t] += u;
        __syncthreads();
    }
    int ex = excl[t] - cnt[t];  // exclusive within bucket
    int node = blk * 256 + t;
    if (node < n) {
        row_ptr[node] = seg0 + ex;
        dinv[node] = rsqrtf((float)cnt[t] + 1.0f);
        if (node == n - 1) row_ptr[n] = seg0 + ex + cnt[t];
    }
    excl[t] = ex;  // becomes fill counter
    __syncthreads();
    for (int i = seg0 + t; i < seg1; i += 256) {
        unsigned pk = packed[i];
        int dl = (pk >> 16) & 255;
        int pos = seg0 + atomicAdd(&excl[dl], 1);
        esrc[pos] = (ushort)(pk & 0xFFFF);
    }
}

// ---------------- MFMA GEMM (G1 only) with LDS-staged epilogue ----------------
template<int K, int NCT, int ACT, int AF32>
__global__ __launch_bounds__(256) void mfma_gemm(
    const void* __restrict__ A, const ushort* __restrict__ Bp,
    const float* __restrict__ bias, void* __restrict__ Cout,
    int M, int ldc, int totct) {
    constexpr int CH = NCT * 16;
    constexpr int CSTR = CH + 4;
    __shared__ float cs[128 * CSTR];

    const int tid = threadIdx.x;
    const int wid = tid >> 6, lane = tid & 63;
    const int ct0 = blockIdx.y * NCT;
    const int rowbase = blockIdx.x * 128 + wid * 32;
    const int ak = (lane >> 4) * 8;

    f32x4 acc[2][NCT];
#pragma unroll
    for (int s = 0; s < 2; s++)
#pragma unroll
        for (int c = 0; c < NCT; c++) acc[s][c] = (f32x4){0.f, 0.f, 0.f, 0.f};

    int r0 = rowbase + (lane & 15); if (r0 >= M) r0 = M - 1;
    int r1 = rowbase + 16 + (lane & 15); if (r1 >= M) r1 = M - 1;
    const float*  a0f = (const float*)A + (size_t)r0 * K + ak;
    const float*  a1f = (const float*)A + (size_t)r1 * K + ak;
    const ushort* a0b = (const ushort*)A + (size_t)r0 * K + ak;
    const ushort* a1b = (const ushort*)A + (size_t)r1 * K + ak;

#pragma unroll
    for (int kt = 0; kt < K / 32; kt++) {
        bf16x8 a0, a1;
        if (AF32) {
            float u[8], v[8];
            *(float4*)u = *(const float4*)(a0f + kt * 32);
            *(float4*)(u + 4) = *(const float4*)(a0f + kt * 32 + 4);
            *(float4*)v = *(const float4*)(a1f + kt * 32);
            *(float4*)(v + 4) = *(const float4*)(a1f + kt * 32 + 4);
#pragma unroll
            for (int j = 0; j < 8; j++) { a0[j] = (short)f2bf(u[j]); a1[j] = (short)f2bf(v[j]); }
        } else {
            a0 = *reinterpret_cast<const bf16x8*>(a0b + kt * 32);
            a1 = *reinterpret_cast<const bf16x8*>(a1b + kt * 32);
        }
        const ushort* bp = Bp + ((size_t)(kt * totct + ct0) * 64 + lane) * 8;
#pragma unroll
        for (int c = 0; c < NCT; c++) {
            bf16x8 b = *reinterpret_cast<const bf16x8*>(bp + (size_t)c * 64 * 8);
            acc[0][c] = __builtin_amdgcn_mfma_f32_16x16x32_bf16(a0, b, acc[0][c], 0, 0, 0);
            acc[1][c] = __builtin_amdgcn_mfma_f32_16x16x32_bf16(a1, b, acc[1][c], 0, 0, 0);
        }
    }

    const int ccol = lane & 15;
    const int crow = (lane >> 4) * 4;
#pragma unroll
    for (int s = 0; s < 2; s++) {
#pragma unroll
        for (int c = 0; c < NCT; c++) {
            float* dstp = cs + (size_t)(wid * 32 + s * 16 + crow) * CSTR + c * 16 + ccol;
#pragma unroll
            for (int r = 0; r < 4; r++)
                dstp[(size_t)r * CSTR] = acc[s][c][r];
        }
    }
    __syncthreads();

    const int rowblk = blockIdx.x * 128;
    const int colbase = ct0 * 16;
    if (ACT == 0 || ACT == 2) {
        constexpr int CPR = CH / 4;
        for (int i = tid; i < 128 * CPR; i += 256) {
            int row = i / CPR, c4 = (i - row * CPR) * 4;
            int grow = rowblk + row;
            if (grow >= M) continue;
            float4 v = *(const float4*)(cs + (size_t)row * CSTR + c4);
            int col = colbase + c4;
            if (bias) {
                float4 bb = *(const float4*)(bias + col);
                v.x += bb.x; v.y += bb.y; v.z += bb.z; v.w += bb.w;
            }
            if (ACT == 2) {
                v.x = 1.f / (1.f + __expf(-v.x));
                v.y = 1.f / (1.f + __expf(-v.y));
                v.z = 1.f / (1.f + __expf(-v.z));
                v.w = 1.f / (1.f + __expf(-v.w));
            }
            *(float4*)((float*)Cout + (size_t)grow * ldc + col) = v;
        }
    } else {
        constexpr int CPR = CH / 8;
        for (int i = tid; i < 128 * CPR; i += 256) {
            int row = i / CPR, c8 = (i - row * CPR) * 8;
            int grow = rowblk + row;
            if (grow >= M) continue;
            int col = colbase + c8;
            float v[8];
            *(float4*)v = *(const float4*)(cs + (size_t)row * CSTR + c8);
            *(float4*)(v + 4) = *(const float4*)(cs + (size_t)row * CSTR + c8 + 4);
            ushort8v o;
#pragma unroll
            for (int j = 0; j < 8; j++) {
                float t = v[j] + (bias ? bias[col + j] : 0.f);
                if (ACT == 1) t = t > 0.f ? t : 0.f;
                o[j] = f2bf(t);
            }
            *(ushort8v*)((ushort*)Cout + (size_t)grow * ldc + col) = o;
        }
    }
}

// ---------------- fused G2+G3, column-split (r21 structure, measured = r20) ----------------
__global__ __launch_bounds__(256) void g2g3_kernel(
    const ushort* __restrict__ outb, const ushort* __restrict__ W1P,
    const float* __restrict__ b1, const ushort* __restrict__ W2P,
    const float* __restrict__ b2, float* __restrict__ fo, int M) {
    constexpr int ZSTR = 136;    // bf16 elems; 272 B row stride
    constexpr int CSTR = 132;    // f32 elems
    __shared__ ushort zlds[64 * ZSTR];  // 17,408 B
    __shared__ float  cs[64 * CSTR];    // 33,792 B

    const int tid = threadIdx.x;
    const int wid = tid >> 6, lane = tid & 63;
    const int rowbase = blockIdx.x * 64 + wid * 16;
    const int pass = blockIdx.y;         // which 128-col half of fo
    const int ak = (lane >> 4) * 8;
    const int ccol = lane & 15;
    const int crow4 = (lane >> 4) * 4;

    // ---- phase 1: z = relu(outb @ W1 + b1), 16 rows/wave, K=128, 128 cols
    f32x4 acc[8];
#pragma unroll
    for (int c = 0; c < 8; c++) acc[c] = (f32x4){0.f, 0.f, 0.f, 0.f};

    int r0 = rowbase + (lane & 15); if (r0 >= M) r0 = M - 1;
    const ushort* a0b = outb + (size_t)r0 * HFEAT + ak;
#pragma unroll
    for (int kt = 0; kt < 4; kt++) {
        bf16x8 a0 = *reinterpret_cast<const bf16x8*>(a0b + kt * 32);
        const ushort* bp = W1P + ((size_t)(kt * 8) * 64 + lane) * 8;
#pragma unroll
        for (int c = 0; c < 8; c++) {
            bf16x8 b = *reinterpret_cast<const bf16x8*>(bp + (size_t)c * 512);
            acc[c] = __builtin_amdgcn_mfma_f32_16x16x32_bf16(a0, b, acc[c], 0, 0, 0);
        }
    }
#pragma unroll
    for (int c = 0; c < 8; c++) {
        float bb = b1[c * 16 + ccol];
        ushort* zp = zlds + (size_t)(wid * 16 + crow4) * ZSTR + c * 16 + ccol;
#pragma unroll
        for (int r = 0; r < 4; r++) {
            float v = acc[c][r] + bb;
            v = v > 0.f ? v : 0.f;
            zp[(size_t)r * ZSTR] = f2bf(v);
        }
    }
    __syncthreads();  // z-writes before z-reads (cross-lane RAW, rule #18)

    // ---- phase 2: ONE 128-col pass (this block's half)
    const int rowblk = blockIdx.x * 64;
    const ushort* z0 = zlds + (size_t)(wid * 16 + (lane & 15)) * ZSTR + ak;
    f32x4 acc2[8];
#pragma unroll
    for (int c = 0; c < 8; c++) acc2[c] = (f32x4){0.f, 0.f, 0.f, 0.f};
#pragma unroll
    for (int kt = 0; kt < 4; kt++) {
        bf16x8 a0 = *reinterpret_cast<const bf16x8*>(z0 + kt * 32);
        const ushort* bp = W2P + ((size_t)(kt * 16 + pass * 8) * 64 + lane) * 8;
#pragma unroll
        for (int c = 0; c < 8; c++) {
            bf16x8 b = *reinterpret_cast<const bf16x8*>(bp + (size_t)c * 512);
            acc2[c] = __builtin_amdgcn_mfma_f32_16x16x32_bf16(a0, b, acc2[c], 0, 0, 0);
        }
    }
#pragma unroll
    for (int c = 0; c < 8; c++) {
        float* dstp = cs + (size_t)(wid * 16 + crow4) * CSTR + c * 16 + ccol;
#pragma unroll
        for (int r = 0; r < 4; r++)
            dstp[(size_t)r * CSTR] = acc2[c][r];
    }
    __syncthreads();
    for (int i = tid; i < 64 * 32; i += 256) {
        int row = i >> 5, c4 = (i & 31) * 4;
        int grow = rowblk + row;
        if (grow >= M) continue;
        float4 v = *(const float4*)(cs + (size_t)row * CSTR + c4);
        int col = pass * 128 + c4;
        float4 bb = *(const float4*)(b2 + col);
        v.x = 1.f / (1.f + __expf(-(v.x + bb.x)));
        v.y = 1.f / (1.f + __expf(-(v.y + bb.y)));
        v.z = 1.f / (1.f + __expf(-(v.z + bb.z)));
        v.w = 1.f / (1.f + __expf(-(v.w + bb.w)));
        *(float4*)(fo + (size_t)grow * FFEAT + col) = v;
    }
}

// ---------------- CSR gather + fused p/q (edge-split halves) ----------------
__global__ __launch_bounds__(256) void gather_pq_kernel(
    const ushort* __restrict__ h, const int* __restrict__ row_ptr,
    const ushort* __restrict__ esrc, const float* __restrict__ dinv,
    const float* __restrict__ bg, const float* __restrict__ Wa,
    ushort* __restrict__ outb, float* __restrict__ p, float* __restrict__ q, int n) {
    int tid = threadIdx.x;
    int node = blockIdx.x * 8 + (tid >> 5);
    int half = (tid >> 4) & 1;
    int c8 = (tid & 15) * 8;
    if (node >= n) return;
    float di = dinv[node];
    int r0 = row_ptr[node], r1 = row_ptr[node + 1];
    float acc[8];
    if (half == 0) {
        ushort8v hv = *(const ushort8v*)(h + (size_t)node * HFEAT + c8);
#pragma unroll
        for (int j = 0; j < 8; j++) acc[j] = bf2f(hv[j]) * di;
    } else {
#pragma unroll
        for (int j = 0; j < 8; j++) acc[j] = 0.f;
    }
    int e = r0 + half;
    for (; e + 2 < r1; e += 4) {
        int s0 = esrc[e], s1 = esrc[e + 2];
        float d0 = dinv[s0], d1 = dinv[s1];
        ushort8v v0 = *(const ushort8v*)(h + (size_t)s0 * HFEAT + c8);
        ushort8v v1 = *(const ushort8v*)(h + (size_t)s1 * HFEAT + c8);
#pragma unroll
        for (int j = 0; j < 8; j++) acc[j] = fmaf(bf2f(v0[j]), d0, acc[j]);
#pragma unroll
        for (int j = 0; j < 8; j++) acc[j] = fmaf(bf2f(v1[j]), d1, acc[j]);
    }
    if (e < r1) {
        int s0 = esrc[e];
        float d0 = dinv[s0];
        ushort8v v0 = *(const ushort8v*)(h + (size_t)s0 * HFEAT + c8);
#pragma unroll
        for (int j = 0; j < 8; j++) acc[j] = fmaf(bf2f(v0[j]), d0, acc[j]);
    }
#pragma unroll
    for (int j = 0; j < 8; j++) acc[j] += __shfl_down(acc[j], 16, 32);
    if (half == 0) {
        float o[8];
        ushort8v ov;
#pragma unroll
        for (int j = 0; j < 8; j++) {
            o[j] = fmaf(acc[j], di, bg[c8 + j]);
            ov[j] = f2bf(o[j]);
        }
        *(ushort8v*)(outb + (size_t)node * HFEAT + c8) = ov;

        float pp = 0.f, qq = 0.f;
#pragma unroll
        for (int j = 0; j < 8; j++) {
            pp = fmaf(o[j], Wa[c8 + j], pp);
            qq = fmaf(o[j], Wa[HFEAT + c8 + j], qq);
        }
        for (int off = 8; off; off >>= 1) {
            pp += __shfl_down(pp, off, 16);
            qq += __shfl_down(qq, off, 16);
        }
        if ((tid & 31) == 0) { p[node] = pp; q[node] = qq; }
    }
}

// ---------------- adjacency scores ----------------
__global__ void adj_kernel(const int* __restrict__ k0, const int* __restrict__ k1,
                           const int2* __restrict__ na, const float* __restrict__ p,
                           const float* __restrict__ q, const float* __restrict__ ba,
                           float* __restrict__ outp, int ek, int en) {
    int e = blockIdx.x * blockDim.x + threadIdx.x;
    int tot = ek + en;
    if (e >= tot) return;
    int a, b;
    if (e < ek) { a = k0[e]; b = k1[e]; }
    else { int2 ab = na[e - ek]; a = ab.x; b = ab.y; }
    float v = p[a] + q[b] + ba[0];
    outp[e] = 1.f / (1.f + __expf(-v));
}

extern "C" void kernel_launch(void* const* d_in, const int* in_sizes, int n_in,
                              void* d_out, int out_size, void* d_ws, size_t ws_size,
                              hipStream_t stream) {
    const float* x  = (const float*)d_in[0];
    const int*   ei = (const int*)d_in[1];
    const int*   kh = (const int*)d_in[2];
    const int*   na = (const int*)d_in[3];
    const float* Wg = (const float*)d_in[4];
    const float* bg = (const float*)d_in[5];
    const float* W1 = (const float*)d_in[6];
    const float* b1 = (const float*)d_in[7];
    const float* W2 = (const float*)d_in[8];
    const float* b2 = (const float*)d_in[9];
    const float* Wa = (const float*)d_in[10];
    const float* ba = (const float*)d_in[11];

    const int N  = in_sizes[0] / FFEAT;
    const int E  = in_sizes[1] / 2;
    const int EK = in_sizes[2] / 2;
    const int EN = in_sizes[3] / 2;

    float* fo = (float*)d_out;             // feature_out [N, 256] f32
    float* ao = fo + (size_t)N * FFEAT;    // adj_out [EK+EN]

    const int NB_C = (E + EPB - 1) / EPB;  // coarse blocks (196 <= 256)
    const int n2 = 256 * NB_C;             // histT elements

    char* ws = (char*)d_ws;
    ushort* h    = (ushort*)ws;  ws += (size_t)N * HFEAT * 2;   // bf16
    ushort* outb = (ushort*)ws;  ws += (size_t)N * HFEAT * 2;
    ushort* WgP  = (ushort*)ws;  ws += (size_t)FFEAT * HFEAT * 2;
    ushort* W1P  = (ushort*)ws;  ws += (size_t)HFEAT * HFEAT * 2;
    ushort* W2P  = (ushort*)ws;  ws += (size_t)HFEAT * FFEAT * 2;
    float*  dinv = (float*)ws;   ws += (size_t)N * 4;
    float*  p    = (float*)ws;   ws += (size_t)N * 4;
    float*  q    = (float*)ws;   ws += (size_t)N * 4;
    int*    row_ptr = (int*)ws;  ws += (size_t)(N + 1) * 4;
    int*    histT = (int*)ws;    ws += (size_t)n2 * 4;
    int*    scanT = (int*)ws;    ws += (size_t)n2 * 4;
    int*    bsum  = (int*)ws;    ws += (size_t)1024 * 4;
    unsigned* packed = (unsigned*)ws; ws += (size_t)E * 4;
    ushort* esrc = (ushort*)ws;  ws += (size_t)E * 2;

    const int B = 256;
    const int GX = (N + 127) / 128;
    const int GB = (N + 63) / 64;

    // CSR build via two-level counting sort (weight pack fused in histA; bscan folded into escan)
    histA_kernel<<<NB_C, B, 0, stream>>>(ei + E, histT, Wg, W1, W2, WgP, W1P, W2P, E, NB_C);
    bsum_kernel<<<NB_C, B, 0, stream>>>(histT, bsum, n2);
    escan_kernel<<<NB_C, B, 0, stream>>>(histT, bsum, scanT, n2);
    scatterC_kernel<<<NB_C, B, 0, stream>>>(ei, ei + E, scanT, packed, E, NB_C);
    fineD_kernel<<<256, B, 0, stream>>>(packed, scanT, esrc, row_ptr, dinv, E, NB_C, N);

    // G1: h = bf16( x(f32) @ Wg ), in-kernel RNE convert, single pass
    mfma_gemm<FFEAT, 8, 3, 1><<<dim3(GX, 1), B, 0, stream>>>(x, WgP, nullptr, h, N, HFEAT, HFEAT / 16);

    // GCN aggregate -> outb (bf16), bias fused, p/q fused
    gather_pq_kernel<<<(N + 7) / 8, B, 0, stream>>>(h, row_ptr, esrc, dinv, bg, Wa, outb, p, q, N);

    // fused G2+G3, column-split (blockIdx.y = fo column half)
    g2g3_kernel<<<dim3(GB, 2), B, 0, stream>>>(outb, W1P, b1, W2P, b2, fo, N);

    // adjacency scores
    adj_kernel<<<(EK + EN + B - 1) / B, B, 0, stream>>>(kh, kh + EK, (const int2*)na, p, q, ba, ao, EK, EN);
}

// Round 23
// 118.231 us; speedup vs baseline: 1.0462x; 1.0374x over previous
//
#include <hip/hip_runtime.h>
#include <cstdint>
#include <cstddef>

#define HFEAT 128
#define FFEAT 256
#define EPB 4096  // edges per block for hist/scatter passes (NB_C = 196 <= 256)
#define PACK_TOTAL (FFEAT * HFEAT + HFEAT * HFEAT + HFEAT * FFEAT)  // 81920

typedef short bf16x8 __attribute__((ext_vector_type(8)));
typedef float f32x4 __attribute__((ext_vector_type(4)));
typedef unsigned short ushort8v __attribute__((ext_vector_type(8)));

static __device__ __forceinline__ unsigned short f2bf(float f) {
    unsigned u = __float_as_uint(f);
    unsigned r = (u + 0x7fff + ((u >> 16) & 1)) >> 16;  // RNE
    return (unsigned short)r;
}
static __device__ __forceinline__ float bf2f(unsigned short u) {
    return __uint_as_float((unsigned)u << 16);
}

// ---------------- weight pack helper ----------------
static __device__ __forceinline__ void pack_one(const float* __restrict__ W,
                                                ushort* __restrict__ Bp,
                                                int tid, int N) {
    int j = tid & 7;
    int lane = (tid >> 3) & 63;
    int rest = tid >> 9;
    int nct = N >> 4;
    int ct = rest % nct, kt = rest / nct;
    int k = kt * 32 + (lane >> 4) * 8 + j;
    int col = ct * 16 + (lane & 15);
    Bp[tid] = f2bf(W[(size_t)k * N + col]);
}

// ---------------- CSR build: two-level counting sort (r17 structure, EPB=4096) ----------------
__global__ __launch_bounds__(256) void histA_kernel(
    const int* __restrict__ dst, int* __restrict__ histT,
    const float* __restrict__ Wg, const float* __restrict__ W1, const float* __restrict__ W2,
    ushort* __restrict__ WgP, ushort* __restrict__ W1P, ushort* __restrict__ W2P,
    int E, int NB_C) {
    __shared__ int hist[256];
    int t = threadIdx.x, b = blockIdx.x;
    hist[t] = 0;
    __syncthreads();

    // fused weight pack (grid-stride)
    for (int idx = b * 256 + t; idx < PACK_TOTAL; idx += NB_C * 256) {
        if (idx < FFEAT * HFEAT) pack_one(Wg, WgP, idx, HFEAT);
        else if (idx < FFEAT * HFEAT + HFEAT * HFEAT) pack_one(W1, W1P, idx - FFEAT * HFEAT, HFEAT);
        else pack_one(W2, W2P, idx - FFEAT * HFEAT - HFEAT * HFEAT, FFEAT);
    }

    int lo = b * EPB, hi = min(E, lo + EPB);
    for (int i = lo + t; i < hi; i += 256)
        atomicAdd(&hist[dst[i] >> 8], 1);
    __syncthreads();
    histT[t * NB_C + b] = hist[t];
}

__global__ __launch_bounds__(256) void bsum_kernel(const int* __restrict__ in,
                                                   int* __restrict__ bsum, int n) {
    int i = blockIdx.x * 256 + threadIdx.x;
    int v = (i < n) ? in[i] : 0;
    for (int off = 32; off; off >>= 1) v += __shfl_down(v, off, 64);
    __shared__ int sh[4];
    if ((threadIdx.x & 63) == 0) sh[threadIdx.x >> 6] = v;
    __syncthreads();
    if (threadIdx.x == 0) bsum[blockIdx.x] = sh[0] + sh[1] + sh[2] + sh[3];
}

// escan with self-computed block offset (NB_C <= 256)
__global__ __launch_bounds__(256) void escan_kernel(const int* __restrict__ in,
                                                    const int* __restrict__ bsum,
                                                    int* __restrict__ out, int n) {
    __shared__ int sh[256];
    int t = threadIdx.x, bx = blockIdx.x;
    int v = (t < bx) ? bsum[t] : 0;
    sh[t] = v;
    __syncthreads();
    for (int off = 128; off; off >>= 1) {
        if (t < off) sh[t] += sh[t + off];
        __syncthreads();
    }
    int boff = sh[0];
    __syncthreads();
    int i = bx * 256 + t;
    int u = (i < n) ? in[i] : 0;
    sh[t] = u;
    __syncthreads();
    for (int off = 1; off < 256; off <<= 1) {
        int w = (t >= off) ? sh[t - off] : 0;
        __syncthreads();
        sh[t] += w;
        __syncthreads();
    }
    if (i < n) out[i] = boff + sh[t] - u;
}

__global__ __launch_bounds__(256) void scatterC_kernel(const int* __restrict__ src,
                                                       const int* __restrict__ dst,
                                                       const int* __restrict__ scanT,
                                                       unsigned* __restrict__ packed,
                                                       int E, int NB_C) {
    __shared__ int base[256];
    __shared__ int fill[256];
    int t = threadIdx.x, b = blockIdx.x;
    base[t] = scanT[t * NB_C + b];
    fill[t] = 0;
    __syncthreads();
    int lo = b * EPB, hi = min(E, lo + EPB);
    for (int i = lo + t; i < hi; i += 256) {
        int d = dst[i], s = src[i];
        int c = d >> 8;
        int pos = base[c] + atomicAdd(&fill[c], 1);
        packed[pos] = ((unsigned)d << 16) | (unsigned)s;
    }
}

__global__ __launch_bounds__(256) void fineD_kernel(const unsigned* __restrict__ packed,
                                                    const int* __restrict__ scanT,
                                                    ushort* __restrict__ esrc,
                                                    int* __restrict__ row_ptr,
                                                    float* __restrict__ dinv,
                                                    int E, int NB_C, int n) {
    __shared__ int cnt[256];
    __shared__ int excl[256];
    int t = threadIdx.x, blk = blockIdx.x;
    int seg0 = scanT[blk * NB_C];
    int seg1 = (blk == 255) ? E : scanT[(blk + 1) * NB_C];
    cnt[t] = 0;
    __syncthreads();
    for (int i = seg0 + t; i < seg1; i += 256)
        atomicAdd(&cnt[(packed[i] >> 16) & 255], 1);
    __syncthreads();
    excl[t] = cnt[t];
    __syncthreads();
    for (int off = 1; off < 256; off <<= 1) {
        int u = (t >= off) ? excl[t - off] : 0;
        __syncthreads();
        excl[t] += u;
        __syncthreads();
    }
    int ex = excl[t] - cnt[t];  // exclusive within bucket
    int node = blk * 256 + t;
    if (node < n) {
        row_ptr[node] = seg0 + ex;
        dinv[node] = rsqrtf((float)cnt[t] + 1.0f);
        if (node == n - 1) row_ptr[n] = seg0 + ex + cnt[t];
    }
    excl[t] = ex;  // becomes fill counter
    __syncthreads();
    for (int i = seg0 + t; i < seg1; i += 256) {
        unsigned pk = packed[i];
        int dl = (pk >> 16) & 255;
        int pos = seg0 + atomicAdd(&excl[dl], 1);
        esrc[pos] = (ushort)(pk & 0xFFFF);
    }
}

// ---------------- MFMA GEMM (G1 only) with LDS-staged epilogue ----------------
template<int K, int NCT, int ACT, int AF32>
__global__ __launch_bounds__(256) void mfma_gemm(
    const void* __restrict__ A, const ushort* __restrict__ Bp,
    const float* __restrict__ bias, void* __restrict__ Cout,
    int M, int ldc, int totct) {
    constexpr int CH = NCT * 16;
    constexpr int CSTR = CH + 4;
    __shared__ float cs[128 * CSTR];

    const int tid = threadIdx.x;
    const int wid = tid >> 6, lane = tid & 63;
    const int ct0 = blockIdx.y * NCT;
    const int rowbase = blockIdx.x * 128 + wid * 32;
    const int ak = (lane >> 4) * 8;

    f32x4 acc[2][NCT];
#pragma unroll
    for (int s = 0; s < 2; s++)
#pragma unroll
        for (int c = 0; c < NCT; c++) acc[s][c] = (f32x4){0.f, 0.f, 0.f, 0.f};

    int r0 = rowbase + (lane & 15); if (r0 >= M) r0 = M - 1;
    int r1 = rowbase + 16 + (lane & 15); if (r1 >= M) r1 = M - 1;
    const float*  a0f = (const float*)A + (size_t)r0 * K + ak;
    const float*  a1f = (const float*)A + (size_t)r1 * K + ak;
    const ushort* a0b = (const ushort*)A + (size_t)r0 * K + ak;
    const ushort* a1b = (const ushort*)A + (size_t)r1 * K + ak;

#pragma unroll
    for (int kt = 0; kt < K / 32; kt++) {
        bf16x8 a0, a1;
        if (AF32) {
            float u[8], v[8];
            *(float4*)u = *(const float4*)(a0f + kt * 32);
            *(float4*)(u + 4) = *(const float4*)(a0f + kt * 32 + 4);
            *(float4*)v = *(const float4*)(a1f + kt * 32);
            *(float4*)(v + 4) = *(const float4*)(a1f + kt * 32 + 4);
#pragma unroll
            for (int j = 0; j < 8; j++) { a0[j] = (short)f2bf(u[j]); a1[j] = (short)f2bf(v[j]); }
        } else {
            a0 = *reinterpret_cast<const bf16x8*>(a0b + kt * 32);
            a1 = *reinterpret_cast<const bf16x8*>(a1b + kt * 32);
        }
        const ushort* bp = Bp + ((size_t)(kt * totct + ct0) * 64 + lane) * 8;
#pragma unroll
        for (int c = 0; c < NCT; c++) {
            bf16x8 b = *reinterpret_cast<const bf16x8*>(bp + (size_t)c * 64 * 8);
            acc[0][c] = __builtin_amdgcn_mfma_f32_16x16x32_bf16(a0, b, acc[0][c], 0, 0, 0);
            acc[1][c] = __builtin_amdgcn_mfma_f32_16x16x32_bf16(a1, b, acc[1][c], 0, 0, 0);
        }
    }

    const int ccol = lane & 15;
    const int crow = (lane >> 4) * 4;
#pragma unroll
    for (int s = 0; s < 2; s++) {
#pragma unroll
        for (int c = 0; c < NCT; c++) {
            float* dstp = cs + (size_t)(wid * 32 + s * 16 + crow) * CSTR + c * 16 + ccol;
#pragma unroll
            for (int r = 0; r < 4; r++)
                dstp[(size_t)r * CSTR] = acc[s][c][r];
        }
    }
    __syncthreads();

    const int rowblk = blockIdx.x * 128;
    const int colbase = ct0 * 16;
    if (ACT == 0 || ACT == 2) {
        constexpr int CPR = CH / 4;
        for (int i = tid; i < 128 * CPR; i += 256) {
            int row = i / CPR, c4 = (i - row * CPR) * 4;
            int grow = rowblk + row;
            if (grow >= M) continue;
            float4 v = *(const float4*)(cs + (size_t)row * CSTR + c4);
            int col = colbase + c4;
            if (bias) {
                float4 bb = *(const float4*)(bias + col);
                v.x += bb.x; v.y += bb.y; v.z += bb.z; v.w += bb.w;
            }
            if (ACT == 2) {
                v.x = 1.f / (1.f + __expf(-v.x));
                v.y = 1.f / (1.f + __expf(-v.y));
                v.z = 1.f / (1.f + __expf(-v.z));
                v.w = 1.f / (1.f + __expf(-v.w));
            }
            *(float4*)((float*)Cout + (size_t)grow * ldc + col) = v;
        }
    } else {
        constexpr int CPR = CH / 8;
        for (int i = tid; i < 128 * CPR; i += 256) {
            int row = i / CPR, c8 = (i - row * CPR) * 8;
            int grow = rowblk + row;
            if (grow >= M) continue;
            int col = colbase + c8;
            float v[8];
            *(float4*)v = *(const float4*)(cs + (size_t)row * CSTR + c8);
            *(float4*)(v + 4) = *(const float4*)(cs + (size_t)row * CSTR + c8 + 4);
            ushort8v o;
#pragma unroll
            for (int j = 0; j < 8; j++) {
                float t = v[j] + (bias ? bias[col + j] : 0.f);
                if (ACT == 1) t = t > 0.f ? t : 0.f;
                o[j] = f2bf(t);
            }
            *(ushort8v*)((ushort*)Cout + (size_t)grow * ldc + col) = o;
        }
    }
}

// ---------------- fused G2+G3, column-split + LDS-union ----------------
// r22 counters: LDS 51,200 B -> 3 blocks/CU -> 20% occupancy was the cap (VGPR only 68).
// Now ONE 17,408 B region time-shared: zlds (64x136 bf16) during phases 1-2, then the
// epilogue stages 2x 64-col sub-stages through the same memory (64x68 f32 = 17,408 B).
// Barrier protocol: z-write -> z-read (RAW); z-read -> stage overwrite (WAR); per
// sub-stage: stage -> read (RAW), read -> next stage (WAR).
__global__ __launch_bounds__(256) void g2g3_kernel(
    const ushort* __restrict__ outb, const ushort* __restrict__ W1P,
    const float* __restrict__ b1, const ushort* __restrict__ W2P,
    const float* __restrict__ b2, float* __restrict__ fo, int M) {
    constexpr int ZSTR = 136;    // bf16 elems; 272 B row stride
    constexpr int CSTRH = 68;    // f32 elems; 272 B row stride (same free 2-way banks)
    __shared__ float smem[4352];        // 17,408 B, time-shared
    ushort* zlds = (ushort*)smem;
    float*  csq  = smem;

    const int tid = threadIdx.x;
    const int wid = tid >> 6, lane = tid & 63;
    const int rowbase = blockIdx.x * 64 + wid * 16;
    const int pass = blockIdx.y;         // which 128-col half of fo
    const int ak = (lane >> 4) * 8;
    const int ccol = lane & 15;
    const int crow4 = (lane >> 4) * 4;

    // ---- phase 1: z = relu(outb @ W1 + b1), 16 rows/wave, K=128, 128 cols
    f32x4 acc[8];
#pragma unroll
    for (int c = 0; c < 8; c++) acc[c] = (f32x4){0.f, 0.f, 0.f, 0.f};

    int r0 = rowbase + (lane & 15); if (r0 >= M) r0 = M - 1;
    const ushort* a0b = outb + (size_t)r0 * HFEAT + ak;
#pragma unroll
    for (int kt = 0; kt < 4; kt++) {
        bf16x8 a0 = *reinterpret_cast<const bf16x8*>(a0b + kt * 32);
        const ushort* bp = W1P + ((size_t)(kt * 8) * 64 + lane) * 8;
#pragma unroll
        for (int c = 0; c < 8; c++) {
            bf16x8 b = *reinterpret_cast<const bf16x8*>(bp + (size_t)c * 512);
            acc[c] = __builtin_amdgcn_mfma_f32_16x16x32_bf16(a0, b, acc[c], 0, 0, 0);
        }
    }
#pragma unroll
    for (int c = 0; c < 8; c++) {
        float bb = b1[c * 16 + ccol];
        ushort* zp = zlds + (size_t)(wid * 16 + crow4) * ZSTR + c * 16 + ccol;
#pragma unroll
        for (int r = 0; r < 4; r++) {
            float v = acc[c][r] + bb;
            v = v > 0.f ? v : 0.f;
            zp[(size_t)r * ZSTR] = f2bf(v);
        }
    }
    __syncthreads();  // z-writes before z-reads (cross-lane RAW, rule #18)

    // ---- phase 2: ONE 128-col pass (this block's half)
    const int rowblk = blockIdx.x * 64;
    const ushort* z0 = zlds + (size_t)(wid * 16 + (lane & 15)) * ZSTR + ak;
    f32x4 acc2[8];
#pragma unroll
    for (int c = 0; c < 8; c++) acc2[c] = (f32x4){0.f, 0.f, 0.f, 0.f};
#pragma unroll
    for (int kt = 0; kt < 4; kt++) {
        bf16x8 a0 = *reinterpret_cast<const bf16x8*>(z0 + kt * 32);
        const ushort* bp = W2P + ((size_t)(kt * 16 + pass * 8) * 64 + lane) * 8;
#pragma unroll
        for (int c = 0; c < 8; c++) {
            bf16x8 b = *reinterpret_cast<const bf16x8*>(bp + (size_t)c * 512);
            acc2[c] = __builtin_amdgcn_mfma_f32_16x16x32_bf16(a0, b, acc2[c], 0, 0, 0);
        }
    }
    __syncthreads();  // all z-reads done before the stage overwrites zlds (WAR)

    // ---- epilogue: two 64-col sub-stages through the shared region
#pragma unroll
    for (int halfc = 0; halfc < 2; halfc++) {
        if (halfc) __syncthreads();  // prior sub-stage reads done (WAR)
#pragma unroll
        for (int c = 0; c < 4; c++) {
            float* dstp = csq + (size_t)(wid * 16 + crow4) * CSTRH + c * 16 + ccol;
#pragma unroll
            for (int r = 0; r < 4; r++)
                dstp[(size_t)r * CSTRH] = acc2[halfc * 4 + c][r];
        }
        __syncthreads();
        for (int i = tid; i < 64 * 16; i += 256) {
            int row = i >> 4, c4 = (i & 15) * 4;
            int grow = rowblk + row;
            if (grow >= M) continue;
            float4 v = *(const float4*)(csq + (size_t)row * CSTRH + c4);
            int col = pass * 128 + halfc * 64 + c4;
            float4 bb = *(const float4*)(b2 + col);
            v.x = 1.f / (1.f + __expf(-(v.x + bb.x)));
            v.y = 1.f / (1.f + __expf(-(v.y + bb.y)));
            v.z = 1.f / (1.f + __expf(-(v.z + bb.z)));
            v.w = 1.f / (1.f + __expf(-(v.w + bb.w)));
            *(float4*)(fo + (size_t)grow * FFEAT + col) = v;
        }
    }
}

// ---------------- CSR gather + fused p/q (edge-split halves) ----------------
__global__ __launch_bounds__(256) void gather_pq_kernel(
    const ushort* __restrict__ h, const int* __restrict__ row_ptr,
    const ushort* __restrict__ esrc, const float* __restrict__ dinv,
    const float* __restrict__ bg, const float* __restrict__ Wa,
    ushort* __restrict__ outb, float* __restrict__ p, float* __restrict__ q, int n) {
    int tid = threadIdx.x;
    int node = blockIdx.x * 8 + (tid >> 5);
    int half = (tid >> 4) & 1;
    int c8 = (tid & 15) * 8;
    if (node >= n) return;
    float di = dinv[node];
    int r0 = row_ptr[node], r1 = row_ptr[node + 1];
    float acc[8];
    if (half == 0) {
        ushort8v hv = *(const ushort8v*)(h + (size_t)node * HFEAT + c8);
#pragma unroll
        for (int j = 0; j < 8; j++) acc[j] = bf2f(hv[j]) * di;
    } else {
#pragma unroll
        for (int j = 0; j < 8; j++) acc[j] = 0.f;
    }
    int e = r0 + half;
    for (; e + 2 < r1; e += 4) {
        int s0 = esrc[e], s1 = esrc[e + 2];
        float d0 = dinv[s0], d1 = dinv[s1];
        ushort8v v0 = *(const ushort8v*)(h + (size_t)s0 * HFEAT + c8);
        ushort8v v1 = *(const ushort8v*)(h + (size_t)s1 * HFEAT + c8);
#pragma unroll
        for (int j = 0; j < 8; j++) acc[j] = fmaf(bf2f(v0[j]), d0, acc[j]);
#pragma unroll
        for (int j = 0; j < 8; j++) acc[j] = fmaf(bf2f(v1[j]), d1, acc[j]);
    }
    if (e < r1) {
        int s0 = esrc[e];
        float d0 = dinv[s0];
        ushort8v v0 = *(const ushort8v*)(h + (size_t)s0 * HFEAT + c8);
#pragma unroll
        for (int j = 0; j < 8; j++) acc[j] = fmaf(bf2f(v0[j]), d0, acc[j]);
    }
#pragma unroll
    for (int j = 0; j < 8; j++) acc[j] += __shfl_down(acc[j], 16, 32);
    if (half == 0) {
        float o[8];
        ushort8v ov;
#pragma unroll
        for (int j = 0; j < 8; j++) {
            o[j] = fmaf(acc[j], di, bg[c8 + j]);
            ov[j] = f2bf(o[j]);
        }
        *(ushort8v*)(outb + (size_t)node * HFEAT + c8) = ov;

        float pp = 0.f, qq = 0.f;
#pragma unroll
        for (int j = 0; j < 8; j++) {
            pp = fmaf(o[j], Wa[c8 + j], pp);
            qq = fmaf(o[j], Wa[HFEAT + c8 + j], qq);
        }
        for (int off = 8; off; off >>= 1) {
            pp += __shfl_down(pp, off, 16);
            qq += __shfl_down(qq, off, 16);
        }
        if ((tid & 31) == 0) { p[node] = pp; q[node] = qq; }
    }
}

// ---------------- adjacency scores ----------------
__global__ void adj_kernel(const int* __restrict__ k0, const int* __restrict__ k1,
                           const int2* __restrict__ na, const float* __restrict__ p,
                           const float* __restrict__ q, const float* __restrict__ ba,
                           float* __restrict__ outp, int ek, int en) {
    int e = blockIdx.x * blockDim.x + threadIdx.x;
    int tot = ek + en;
    if (e >= tot) return;
    int a, b;
    if (e < ek) { a = k0[e]; b = k1[e]; }
    else { int2 ab = na[e - ek]; a = ab.x; b = ab.y; }
    float v = p[a] + q[b] + ba[0];
    outp[e] = 1.f / (1.f + __expf(-v));
}

extern "C" void kernel_launch(void* const* d_in, const int* in_sizes, int n_in,
                              void* d_out, int out_size, void* d_ws, size_t ws_size,
                              hipStream_t stream) {
    const float* x  = (const float*)d_in[0];
    const int*   ei = (const int*)d_in[1];
    const int*   kh = (const int*)d_in[2];
    const int*   na = (const int*)d_in[3];
    const float* Wg = (const float*)d_in[4];
    const float* bg = (const float*)d_in[5];
    const float* W1 = (const float*)d_in[6];
    const float* b1 = (const float*)d_in[7];
    const float* W2 = (const float*)d_in[8];
    const float* b2 = (const float*)d_in[9];
    const float* Wa = (const float*)d_in[10];
    const float* ba = (const float*)d_in[11];

    const int N  = in_sizes[0] / FFEAT;
    const int E  = in_sizes[1] / 2;
    const int EK = in_sizes[2] / 2;
    const int EN = in_sizes[3] / 2;

    float* fo = (float*)d_out;             // feature_out [N, 256] f32
    float* ao = fo + (size_t)N * FFEAT;    // adj_out [EK+EN]

    const int NB_C = (E + EPB - 1) / EPB;  // coarse blocks (196 <= 256)
    const int n2 = 256 * NB_C;             // histT elements

    char* ws = (char*)d_ws;
    ushort* h    = (ushort*)ws;  ws += (size_t)N * HFEAT * 2;   // bf16
    ushort* outb = (ushort*)ws;  ws += (size_t)N * HFEAT * 2;
    ushort* WgP  = (ushort*)ws;  ws += (size_t)FFEAT * HFEAT * 2;
    ushort* W1P  = (ushort*)ws;  ws += (size_t)HFEAT * HFEAT * 2;
    ushort* W2P  = (ushort*)ws;  ws += (size_t)HFEAT * FFEAT * 2;
    float*  dinv = (float*)ws;   ws += (size_t)N * 4;
    float*  p    = (float*)ws;   ws += (size_t)N * 4;
    float*  q    = (float*)ws;   ws += (size_t)N * 4;
    int*    row_ptr = (int*)ws;  ws += (size_t)(N + 1) * 4;
    int*    histT = (int*)ws;    ws += (size_t)n2 * 4;
    int*    scanT = (int*)ws;    ws += (size_t)n2 * 4;
    int*    bsum  = (int*)ws;    ws += (size_t)1024 * 4;
    unsigned* packed = (unsigned*)ws; ws += (size_t)E * 4;
    ushort* esrc = (ushort*)ws;  ws += (size_t)E * 2;

    const int B = 256;
    const int GX = (N + 127) / 128;
    const int GB = (N + 63) / 64;

    // CSR build via two-level counting sort (weight pack fused in histA)
    histA_kernel<<<NB_C, B, 0, stream>>>(ei + E, histT, Wg, W1, W2, WgP, W1P, W2P, E, NB_C);
    bsum_kernel<<<NB_C, B, 0, stream>>>(histT, bsum, n2);
    escan_kernel<<<NB_C, B, 0, stream>>>(histT, bsum, scanT, n2);
    scatterC_kernel<<<NB_C, B, 0, stream>>>(ei, ei + E, scanT, packed, E, NB_C);
    fineD_kernel<<<256, B, 0, stream>>>(packed, scanT, esrc, row_ptr, dinv, E, NB_C, N);

    // G1: h = bf16( x(f32) @ Wg ), in-kernel RNE convert, single pass
    mfma_gemm<FFEAT, 8, 3, 1><<<dim3(GX, 1), B, 0, stream>>>(x, WgP, nullptr, h, N, HFEAT, HFEAT / 16);

    // GCN aggregate -> outb (bf16), bias fused, p/q fused
    gather_pq_kernel<<<(N + 7) / 8, B, 0, stream>>>(h, row_ptr, esrc, dinv, bg, Wa, outb, p, q, N);

    // fused G2+G3, column-split + LDS-union (17.4 KB -> 8 blocks/CU)
    g2g3_kernel<<<dim3(GB, 2), B, 0, stream>>>(outb, W1P, b1, W2P, b2, fo, N);

    // adjacency scores
    adj_kernel<<<(EK + EN + B - 1) / B, B, 0, stream>>>(kh, kh + EK, (const int2*)na, p, q, ba, ao, EK, EN);
}

// Round 24
// 114.882 us; speedup vs baseline: 1.0767x; 1.0292x over previous
//
#include <hip/hip_runtime.h>
#include <cstdint>
#include <cstddef>

#define HFEAT 128
#define FFEAT 256
#define EPB 4096  // edges per block for hist/scatter passes (NB_C = 196 <= 256)
#define PACK_TOTAL (FFEAT * HFEAT + HFEAT * HFEAT + HFEAT * FFEAT)  // 81920

typedef short bf16x8 __attribute__((ext_vector_type(8)));
typedef float f32x4 __attribute__((ext_vector_type(4)));
typedef unsigned short ushort8v __attribute__((ext_vector_type(8)));

static __device__ __forceinline__ unsigned short f2bf(float f) {
    unsigned u = __float_as_uint(f);
    unsigned r = (u + 0x7fff + ((u >> 16) & 1)) >> 16;  // RNE
    return (unsigned short)r;
}
static __device__ __forceinline__ float bf2f(unsigned short u) {
    return __uint_as_float((unsigned)u << 16);
}

// ---------------- weight pack helper ----------------
static __device__ __forceinline__ void pack_one(const float* __restrict__ W,
                                                ushort* __restrict__ Bp,
                                                int tid, int N) {
    int j = tid & 7;
    int lane = (tid >> 3) & 63;
    int rest = tid >> 9;
    int nct = N >> 4;
    int ct = rest % nct, kt = rest / nct;
    int k = kt * 32 + (lane >> 4) * 8 + j;
    int col = ct * 16 + (lane & 15);
    Bp[tid] = f2bf(W[(size_t)k * N + col]);
}

// ---------------- CSR build: two-level counting sort ----------------
__global__ __launch_bounds__(256) void histA_kernel(
    const int* __restrict__ dst, int* __restrict__ histT,
    const float* __restrict__ Wg, const float* __restrict__ W1, const float* __restrict__ W2,
    ushort* __restrict__ WgP, ushort* __restrict__ W1P, ushort* __restrict__ W2P,
    int E, int NB_C) {
    __shared__ int hist[256];
    int t = threadIdx.x, b = blockIdx.x;
    hist[t] = 0;
    __syncthreads();

    // fused weight pack (grid-stride)
    for (int idx = b * 256 + t; idx < PACK_TOTAL; idx += NB_C * 256) {
        if (idx < FFEAT * HFEAT) pack_one(Wg, WgP, idx, HFEAT);
        else if (idx < FFEAT * HFEAT + HFEAT * HFEAT) pack_one(W1, W1P, idx - FFEAT * HFEAT, HFEAT);
        else pack_one(W2, W2P, idx - FFEAT * HFEAT - HFEAT * HFEAT, FFEAT);
    }

    int lo = b * EPB, hi = min(E, lo + EPB);
    for (int i = lo + t; i < hi; i += 256)
        atomicAdd(&hist[dst[i] >> 8], 1);
    __syncthreads();
    histT[t * NB_C + b] = hist[t];
}

__global__ __launch_bounds__(256) void bsum_kernel(const int* __restrict__ in,
                                                   int* __restrict__ bsum, int n) {
    int i = blockIdx.x * 256 + threadIdx.x;
    int v = (i < n) ? in[i] : 0;
    for (int off = 32; off; off >>= 1) v += __shfl_down(v, off, 64);
    __shared__ int sh[4];
    if ((threadIdx.x & 63) == 0) sh[threadIdx.x >> 6] = v;
    __syncthreads();
    if (threadIdx.x == 0) bsum[blockIdx.x] = sh[0] + sh[1] + sh[2] + sh[3];
}

// escan with self-computed block offset (NB_C <= 256)
__global__ __launch_bounds__(256) void escan_kernel(const int* __restrict__ in,
                                                    const int* __restrict__ bsum,
                                                    int* __restrict__ out, int n) {
    __shared__ int sh[256];
    int t = threadIdx.x, bx = blockIdx.x;
    int v = (t < bx) ? bsum[t] : 0;
    sh[t] = v;
    __syncthreads();
    for (int off = 128; off; off >>= 1) {
        if (t < off) sh[t] += sh[t + off];
        __syncthreads();
    }
    int boff = sh[0];
    __syncthreads();
    int i = bx * 256 + t;
    int u = (i < n) ? in[i] : 0;
    sh[t] = u;
    __syncthreads();
    for (int off = 1; off < 256; off <<= 1) {
        int w = (t >= off) ? sh[t - off] : 0;
        __syncthreads();
        sh[t] += w;
        __syncthreads();
    }
    if (i < n) out[i] = boff + sh[t] - u;
}

__global__ __launch_bounds__(256) void scatterC_kernel(const int* __restrict__ src,
                                                       const int* __restrict__ dst,
                                                       const int* __restrict__ scanT,
                                                       unsigned* __restrict__ packed,
                                                       int E, int NB_C) {
    __shared__ int base[256];
    __shared__ int fill[256];
    int t = threadIdx.x, b = blockIdx.x;
    base[t] = scanT[t * NB_C + b];
    fill[t] = 0;
    __syncthreads();
    int lo = b * EPB, hi = min(E, lo + EPB);
    for (int i = lo + t; i < hi; i += 256) {
        int d = dst[i], s = src[i];
        int c = d >> 8;
        int pos = base[c] + atomicAdd(&fill[c], 1);
        packed[pos] = ((unsigned)d << 16) | (unsigned)s;
    }
}

__global__ __launch_bounds__(256) void fineD_kernel(const unsigned* __restrict__ packed,
                                                    const int* __restrict__ scanT,
                                                    ushort* __restrict__ esrc,
                                                    int* __restrict__ row_ptr,
                                                    float* __restrict__ dinv,
                                                    int E, int NB_C, int n) {
    __shared__ int cnt[256];
    __shared__ int excl[256];
    int t = threadIdx.x, blk = blockIdx.x;
    int seg0 = scanT[blk * NB_C];
    int seg1 = (blk == 255) ? E : scanT[(blk + 1) * NB_C];
    cnt[t] = 0;
    __syncthreads();
    for (int i = seg0 + t; i < seg1; i += 256)
        atomicAdd(&cnt[(packed[i] >> 16) & 255], 1);
    __syncthreads();
    excl[t] = cnt[t];
    __syncthreads();
    for (int off = 1; off < 256; off <<= 1) {
        int u = (t >= off) ? excl[t - off] : 0;
        __syncthreads();
        excl[t] += u;
        __syncthreads();
    }
    int ex = excl[t] - cnt[t];  // exclusive within bucket
    int node = blk * 256 + t;
    if (node < n) {
        row_ptr[node] = seg0 + ex;
        dinv[node] = rsqrtf((float)cnt[t] + 1.0f);
        if (node == n - 1) row_ptr[n] = seg0 + ex + cnt[t];
    }
    excl[t] = ex;  // becomes fill counter
    __syncthreads();
    for (int i = seg0 + t; i < seg1; i += 256) {
        unsigned pk = packed[i];
        int dl = (pk >> 16) & 255;
        int pos = seg0 + atomicAdd(&excl[dl], 1);
        esrc[pos] = (ushort)(pk & 0xFFFF);
    }
}

// ---------------- MFMA GEMM (G1 only) with LDS-staged epilogue ----------------
template<int K, int NCT, int ACT, int AF32>
__global__ __launch_bounds__(256) void mfma_gemm(
    const void* __restrict__ A, const ushort* __restrict__ Bp,
    const float* __restrict__ bias, void* __restrict__ Cout,
    int M, int ldc, int totct) {
    constexpr int CH = NCT * 16;
    constexpr int CSTR = CH + 4;
    __shared__ float cs[128 * CSTR];

    const int tid = threadIdx.x;
    const int wid = tid >> 6, lane = tid & 63;
    const int ct0 = blockIdx.y * NCT;
    const int rowbase = blockIdx.x * 128 + wid * 32;
    const int ak = (lane >> 4) * 8;

    f32x4 acc[2][NCT];
#pragma unroll
    for (int s = 0; s < 2; s++)
#pragma unroll
        for (int c = 0; c < NCT; c++) acc[s][c] = (f32x4){0.f, 0.f, 0.f, 0.f};

    int r0 = rowbase + (lane & 15); if (r0 >= M) r0 = M - 1;
    int r1 = rowbase + 16 + (lane & 15); if (r1 >= M) r1 = M - 1;
    const float*  a0f = (const float*)A + (size_t)r0 * K + ak;
    const float*  a1f = (const float*)A + (size_t)r1 * K + ak;
    const ushort* a0b = (const ushort*)A + (size_t)r0 * K + ak;
    const ushort* a1b = (const ushort*)A + (size_t)r1 * K + ak;

#pragma unroll
    for (int kt = 0; kt < K / 32; kt++) {
        bf16x8 a0, a1;
        if (AF32) {
            float u[8], v[8];
            *(float4*)u = *(const float4*)(a0f + kt * 32);
            *(float4*)(u + 4) = *(const float4*)(a0f + kt * 32 + 4);
            *(float4*)v = *(const float4*)(a1f + kt * 32);
            *(float4*)(v + 4) = *(const float4*)(a1f + kt * 32 + 4);
#pragma unroll
            for (int j = 0; j < 8; j++) { a0[j] = (short)f2bf(u[j]); a1[j] = (short)f2bf(v[j]); }
        } else {
            a0 = *reinterpret_cast<const bf16x8*>(a0b + kt * 32);
            a1 = *reinterpret_cast<const bf16x8*>(a1b + kt * 32);
        }
        const ushort* bp = Bp + ((size_t)(kt * totct + ct0) * 64 + lane) * 8;
#pragma unroll
        for (int c = 0; c < NCT; c++) {
            bf16x8 b = *reinterpret_cast<const bf16x8*>(bp + (size_t)c * 64 * 8);
            acc[0][c] = __builtin_amdgcn_mfma_f32_16x16x32_bf16(a0, b, acc[0][c], 0, 0, 0);
            acc[1][c] = __builtin_amdgcn_mfma_f32_16x16x32_bf16(a1, b, acc[1][c], 0, 0, 0);
        }
    }

    const int ccol = lane & 15;
    const int crow = (lane >> 4) * 4;
#pragma unroll
    for (int s = 0; s < 2; s++) {
#pragma unroll
        for (int c = 0; c < NCT; c++) {
            float* dstp = cs + (size_t)(wid * 32 + s * 16 + crow) * CSTR + c * 16 + ccol;
#pragma unroll
            for (int r = 0; r < 4; r++)
                dstp[(size_t)r * CSTR] = acc[s][c][r];
        }
    }
    __syncthreads();

    const int rowblk = blockIdx.x * 128;
    const int colbase = ct0 * 16;
    if (ACT == 0 || ACT == 2) {
        constexpr int CPR = CH / 4;
        for (int i = tid; i < 128 * CPR; i += 256) {
            int row = i / CPR, c4 = (i - row * CPR) * 4;
            int grow = rowblk + row;
            if (grow >= M) continue;
            float4 v = *(const float4*)(cs + (size_t)row * CSTR + c4);
            int col = colbase + c4;
            if (bias) {
                float4 bb = *(const float4*)(bias + col);
                v.x += bb.x; v.y += bb.y; v.z += bb.z; v.w += bb.w;
            }
            if (ACT == 2) {
                v.x = 1.f / (1.f + __expf(-v.x));
                v.y = 1.f / (1.f + __expf(-v.y));
                v.z = 1.f / (1.f + __expf(-v.z));
                v.w = 1.f / (1.f + __expf(-v.w));
            }
            *(float4*)((float*)Cout + (size_t)grow * ldc + col) = v;
        }
    } else {
        constexpr int CPR = CH / 8;
        for (int i = tid; i < 128 * CPR; i += 256) {
            int row = i / CPR, c8 = (i - row * CPR) * 8;
            int grow = rowblk + row;
            if (grow >= M) continue;
            int col = colbase + c8;
            float v[8];
            *(float4*)v = *(const float4*)(cs + (size_t)row * CSTR + c8);
            *(float4*)(v + 4) = *(const float4*)(cs + (size_t)row * CSTR + c8 + 4);
            ushort8v o;
#pragma unroll
            for (int j = 0; j < 8; j++) {
                float t = v[j] + (bias ? bias[col + j] : 0.f);
                if (ACT == 1) t = t > 0.f ? t : 0.f;
                o[j] = f2bf(t);
            }
            *(ushort8v*)((ushort*)Cout + (size_t)grow * ldc + col) = o;
        }
    }
}

// ---------------- fused G2+G3 (col-split + LDS-union) + adj slice ----------------
// blockIdx.y in {0,1}: fo column half. blockIdx.y == 2: adjacency scores (p/q were
// written by gather_pq in the PRIOR launch, so they're ready; ao is disjoint from fo).
// Absorbing adj removes one launch+gap and hides its latency-bound gathers under the
// MFMA blocks' execution.
__global__ __launch_bounds__(256) void g2g3_kernel(
    const ushort* __restrict__ outb, const ushort* __restrict__ W1P,
    const float* __restrict__ b1, const ushort* __restrict__ W2P,
    const float* __restrict__ b2, float* __restrict__ fo, int M,
    const int* __restrict__ k0, const int* __restrict__ k1,
    const int2* __restrict__ na, const float* __restrict__ p,
    const float* __restrict__ q, const float* __restrict__ ba,
    float* __restrict__ ao, int ek, int en) {
    constexpr int ZSTR = 136;    // bf16 elems; 272 B row stride
    constexpr int CSTRH = 68;    // f32 elems; 272 B row stride
    __shared__ float smem[4352];        // 17,408 B, time-shared
    ushort* zlds = (ushort*)smem;
    float*  csq  = smem;

    const int tid = threadIdx.x;
    const int pass = blockIdx.y;

    if (pass == 2) {
        // ---- adjacency slice: grid-stride over EK+EN edges
        float bb = ba[0];
        int tot = ek + en;
        for (int e = blockIdx.x * 256 + tid; e < tot; e += gridDim.x * 256) {
            int a, b;
            if (e < ek) { a = k0[e]; b = k1[e]; }
            else { int2 ab = na[e - ek]; a = ab.x; b = ab.y; }
            float v = p[a] + q[b] + bb;
            ao[e] = 1.f / (1.f + __expf(-v));
        }
        return;
    }

    const int wid = tid >> 6, lane = tid & 63;
    const int rowbase = blockIdx.x * 64 + wid * 16;
    const int ak = (lane >> 4) * 8;
    const int ccol = lane & 15;
    const int crow4 = (lane >> 4) * 4;

    // ---- phase 1: z = relu(outb @ W1 + b1), 16 rows/wave, K=128, 128 cols
    f32x4 acc[8];
#pragma unroll
    for (int c = 0; c < 8; c++) acc[c] = (f32x4){0.f, 0.f, 0.f, 0.f};

    int r0 = rowbase + (lane & 15); if (r0 >= M) r0 = M - 1;
    const ushort* a0b = outb + (size_t)r0 * HFEAT + ak;
#pragma unroll
    for (int kt = 0; kt < 4; kt++) {
        bf16x8 a0 = *reinterpret_cast<const bf16x8*>(a0b + kt * 32);
        const ushort* bp = W1P + ((size_t)(kt * 8) * 64 + lane) * 8;
#pragma unroll
        for (int c = 0; c < 8; c++) {
            bf16x8 b = *reinterpret_cast<const bf16x8*>(bp + (size_t)c * 512);
            acc[c] = __builtin_amdgcn_mfma_f32_16x16x32_bf16(a0, b, acc[c], 0, 0, 0);
        }
    }
#pragma unroll
    for (int c = 0; c < 8; c++) {
        float bb = b1[c * 16 + ccol];
        ushort* zp = zlds + (size_t)(wid * 16 + crow4) * ZSTR + c * 16 + ccol;
#pragma unroll
        for (int r = 0; r < 4; r++) {
            float v = acc[c][r] + bb;
            v = v > 0.f ? v : 0.f;
            zp[(size_t)r * ZSTR] = f2bf(v);
        }
    }
    __syncthreads();  // z-writes before z-reads (cross-lane RAW, rule #18)

    // ---- phase 2: ONE 128-col pass (this block's half)
    const int rowblk = blockIdx.x * 64;
    const ushort* z0 = zlds + (size_t)(wid * 16 + (lane & 15)) * ZSTR + ak;
    f32x4 acc2[8];
#pragma unroll
    for (int c = 0; c < 8; c++) acc2[c] = (f32x4){0.f, 0.f, 0.f, 0.f};
#pragma unroll
    for (int kt = 0; kt < 4; kt++) {
        bf16x8 a0 = *reinterpret_cast<const bf16x8*>(z0 + kt * 32);
        const ushort* bp = W2P + ((size_t)(kt * 16 + pass * 8) * 64 + lane) * 8;
#pragma unroll
        for (int c = 0; c < 8; c++) {
            bf16x8 b = *reinterpret_cast<const bf16x8*>(bp + (size_t)c * 512);
            acc2[c] = __builtin_amdgcn_mfma_f32_16x16x32_bf16(a0, b, acc2[c], 0, 0, 0);
        }
    }
    __syncthreads();  // all z-reads done before the stage overwrites zlds (WAR)

    // ---- epilogue: two 64-col sub-stages through the shared region
#pragma unroll
    for (int halfc = 0; halfc < 2; halfc++) {
        if (halfc) __syncthreads();  // prior sub-stage reads done (WAR)
#pragma unroll
        for (int c = 0; c < 4; c++) {
            float* dstp = csq + (size_t)(wid * 16 + crow4) * CSTRH + c * 16 + ccol;
#pragma unroll
            for (int r = 0; r < 4; r++)
                dstp[(size_t)r * CSTRH] = acc2[halfc * 4 + c][r];
        }
        __syncthreads();
        for (int i = tid; i < 64 * 16; i += 256) {
            int row = i >> 4, c4 = (i & 15) * 4;
            int grow = rowblk + row;
            if (grow >= M) continue;
            float4 v = *(const float4*)(csq + (size_t)row * CSTRH + c4);
            int col = pass * 128 + halfc * 64 + c4;
            float4 bb = *(const float4*)(b2 + col);
            v.x = 1.f / (1.f + __expf(-(v.x + bb.x)));
            v.y = 1.f / (1.f + __expf(-(v.y + bb.y)));
            v.z = 1.f / (1.f + __expf(-(v.z + bb.z)));
            v.w = 1.f / (1.f + __expf(-(v.w + bb.w)));
            *(float4*)(fo + (size_t)grow * FFEAT + col) = v;
        }
    }
}

// ---------------- CSR gather + fused p/q (edge-split halves) ----------------
__global__ __launch_bounds__(256) void gather_pq_kernel(
    const ushort* __restrict__ h, const int* __restrict__ row_ptr,
    const ushort* __restrict__ esrc, const float* __restrict__ dinv,
    const float* __restrict__ bg, const float* __restrict__ Wa,
    ushort* __restrict__ outb, float* __restrict__ p, float* __restrict__ q, int n) {
    int tid = threadIdx.x;
    int node = blockIdx.x * 8 + (tid >> 5);
    int half = (tid >> 4) & 1;
    int c8 = (tid & 15) * 8;
    if (node >= n) return;
    float di = dinv[node];
    int r0 = row_ptr[node], r1 = row_ptr[node + 1];
    float acc[8];
    if (half == 0) {
        ushort8v hv = *(const ushort8v*)(h + (size_t)node * HFEAT + c8);
#pragma unroll
        for (int j = 0; j < 8; j++) acc[j] = bf2f(hv[j]) * di;
    } else {
#pragma unroll
        for (int j = 0; j < 8; j++) acc[j] = 0.f;
    }
    int e = r0 + half;
    for (; e + 2 < r1; e += 4) {
        int s0 = esrc[e], s1 = esrc[e + 2];
        float d0 = dinv[s0], d1 = dinv[s1];
        ushort8v v0 = *(const ushort8v*)(h + (size_t)s0 * HFEAT + c8);
        ushort8v v1 = *(const ushort8v*)(h + (size_t)s1 * HFEAT + c8);
#pragma unroll
        for (int j = 0; j < 8; j++) acc[j] = fmaf(bf2f(v0[j]), d0, acc[j]);
#pragma unroll
        for (int j = 0; j < 8; j++) acc[j] = fmaf(bf2f(v1[j]), d1, acc[j]);
    }
    if (e < r1) {
        int s0 = esrc[e];
        float d0 = dinv[s0];
        ushort8v v0 = *(const ushort8v*)(h + (size_t)s0 * HFEAT + c8);
#pragma unroll
        for (int j = 0; j < 8; j++) acc[j] = fmaf(bf2f(v0[j]), d0, acc[j]);
    }
#pragma unroll
    for (int j = 0; j < 8; j++) acc[j] += __shfl_down(acc[j], 16, 32);
    if (half == 0) {
        float o[8];
        ushort8v ov;
#pragma unroll
        for (int j = 0; j < 8; j++) {
            o[j] = fmaf(acc[j], di, bg[c8 + j]);
            ov[j] = f2bf(o[j]);
        }
        *(ushort8v*)(outb + (size_t)node * HFEAT + c8) = ov;

        float pp = 0.f, qq = 0.f;
#pragma unroll
        for (int j = 0; j < 8; j++) {
            pp = fmaf(o[j], Wa[c8 + j], pp);
            qq = fmaf(o[j], Wa[HFEAT + c8 + j], qq);
        }
        for (int off = 8; off; off >>= 1) {
            pp += __shfl_down(pp, off, 16);
            qq += __shfl_down(qq, off, 16);
        }
        if ((tid & 31) == 0) { p[node] = pp; q[node] = qq; }
    }
}

extern "C" void kernel_launch(void* const* d_in, const int* in_sizes, int n_in,
                              void* d_out, int out_size, void* d_ws, size_t ws_size,
                              hipStream_t stream) {
    const float* x  = (const float*)d_in[0];
    const int*   ei = (const int*)d_in[1];
    const int*   kh = (const int*)d_in[2];
    const int*   na = (const int*)d_in[3];
    const float* Wg = (const float*)d_in[4];
    const float* bg = (const float*)d_in[5];
    const float* W1 = (const float*)d_in[6];
    const float* b1 = (const float*)d_in[7];
    const float* W2 = (const float*)d_in[8];
    const float* b2 = (const float*)d_in[9];
    const float* Wa = (const float*)d_in[10];
    const float* ba = (const float*)d_in[11];

    const int N  = in_sizes[0] / FFEAT;
    const int E  = in_sizes[1] / 2;
    const int EK = in_sizes[2] / 2;
    const int EN = in_sizes[3] / 2;

    float* fo = (float*)d_out;             // feature_out [N, 256] f32
    float* ao = fo + (size_t)N * FFEAT;    // adj_out [EK+EN]

    const int NB_C = (E + EPB - 1) / EPB;  // coarse blocks (196 <= 256)
    const int n2 = 256 * NB_C;             // histT elements

    char* ws = (char*)d_ws;
    ushort* h    = (ushort*)ws;  ws += (size_t)N * HFEAT * 2;   // bf16
    ushort* outb = (ushort*)ws;  ws += (size_t)N * HFEAT * 2;
    ushort* WgP  = (ushort*)ws;  ws += (size_t)FFEAT * HFEAT * 2;
    ushort* W1P  = (ushort*)ws;  ws += (size_t)HFEAT * HFEAT * 2;
    ushort* W2P  = (ushort*)ws;  ws += (size_t)HFEAT * FFEAT * 2;
    float*  dinv = (float*)ws;   ws += (size_t)N * 4;
    float*  p    = (float*)ws;   ws += (size_t)N * 4;
    float*  q    = (float*)ws;   ws += (size_t)N * 4;
    int*    row_ptr = (int*)ws;  ws += (size_t)(N + 1) * 4;
    int*    histT = (int*)ws;    ws += (size_t)n2 * 4;
    int*    scanT = (int*)ws;    ws += (size_t)n2 * 4;
    int*    bsum  = (int*)ws;    ws += (size_t)1024 * 4;
    unsigned* packed = (unsigned*)ws; ws += (size_t)E * 4;
    ushort* esrc = (ushort*)ws;  ws += (size_t)E * 2;

    const int B = 256;
    const int GX = (N + 127) / 128;
    const int GB = (N + 63) / 64;

    // CSR build via two-level counting sort (weight pack fused in histA)
    histA_kernel<<<NB_C, B, 0, stream>>>(ei + E, histT, Wg, W1, W2, WgP, W1P, W2P, E, NB_C);
    bsum_kernel<<<NB_C, B, 0, stream>>>(histT, bsum, n2);
    escan_kernel<<<NB_C, B, 0, stream>>>(histT, bsum, scanT, n2);
    scatterC_kernel<<<NB_C, B, 0, stream>>>(ei, ei + E, scanT, packed, E, NB_C);
    fineD_kernel<<<256, B, 0, stream>>>(packed, scanT, esrc, row_ptr, dinv, E, NB_C, N);

    // G1: h = bf16( x(f32) @ Wg ), in-kernel RNE convert, single pass
    mfma_gemm<FFEAT, 8, 3, 1><<<dim3(GX, 1), B, 0, stream>>>(x, WgP, nullptr, h, N, HFEAT, HFEAT / 16);

    // GCN aggregate -> outb (bf16), bias fused, p/q fused
    gather_pq_kernel<<<(N + 7) / 8, B, 0, stream>>>(h, row_ptr, esrc, dinv, bg, Wa, outb, p, q, N);

    // fused G2+G3 (col-split + LDS-union) with adj as blockIdx.y==2 slice
    g2g3_kernel<<<dim3(GB, 3), B, 0, stream>>>(outb, W1P, b1, W2P, b2, fo, N,
                                               kh, kh + EK, (const int2*)na, p, q, ba,
                                               ao, EK, EN);
}